// Round 7
// baseline (240.038 us; speedup 1.0000x reference)
//
#include <hip/hip_runtime.h>
#include <math.h>

#define BB 8
#define TT 1024
#define CC 768
#define NH 12
#define HD 64
#define LOG2E 1.44269504088896f

typedef __attribute__((ext_vector_type(8))) _Float16 hv8;   // 8 fp16 (4 VGPRs)
typedef __attribute__((ext_vector_type(4))) _Float16 hv4;   // 4 fp16 (2 VGPRs)
typedef __attribute__((ext_vector_type(8))) short  short8;  // raw 16B
typedef __attribute__((ext_vector_type(4))) float  f32x4;

static __device__ __forceinline__ float fast_exp2(float x) {
#if __has_builtin(__builtin_amdgcn_exp2f)
    return __builtin_amdgcn_exp2f(x);
#else
    return exp2f(x);
#endif
}

// Async global->LDS DMA, 16B per lane (global_load_lds_dwordx4).
static __device__ __forceinline__ void gload_lds16(
    const _Float16* __restrict__ g, _Float16* l)
{
    __builtin_amdgcn_global_load_lds(
        (const __attribute__((address_space(1))) void*)g,
        (__attribute__((address_space(3))) void*)l, 16, 0, 0);
}

// ---------------------------------------------------------------------------
// Fused prep -- fp32->fp16 convert of x/ctx (blocks 0..6143) AND the 4
// weight transposes (blocks 6144..6719).  Wk carries 0.125*log2e.
// ---------------------------------------------------------------------------
__global__ __launch_bounds__(256) void prep_fused(
    const float* __restrict__ x, const float* __restrict__ ctx,
    _Float16* __restrict__ xh, _Float16* __restrict__ ch, int n,
    const float* __restrict__ Wq, const float* __restrict__ Wk,
    const float* __restrict__ Wv, const float* __restrict__ Wo,
    _Float16* __restrict__ WqT, _Float16* __restrict__ WkT,
    _Float16* __restrict__ WvT, _Float16* __restrict__ WoT)
{
    __shared__ float tile[64][65];
    const int bid = blockIdx.x;

    if (bid < 6144) {
        const float* in = (bid >= 3072) ? ctx : x;
        _Float16* out   = (bid >= 3072) ? ch  : xh;
        int bb2 = (bid >= 3072) ? bid - 3072 : bid;
        int i = (bb2 * 256 + threadIdx.x) * 8;
        if (i < n) {
            float4 v0 = *(const float4*)(in + i);
            float4 v1 = *(const float4*)(in + i + 4);
            hv8 h = { (_Float16)v0.x, (_Float16)v0.y, (_Float16)v0.z, (_Float16)v0.w,
                      (_Float16)v1.x, (_Float16)v1.y, (_Float16)v1.z, (_Float16)v1.w };
            *(hv8*)(out + i) = h;
        }
        return;
    }

    const int t  = bid - 6144;            // 0..575
    const int z  = t / 144;
    const int rm = t - z * 144;
    const int by = rm / 12, bx = rm - by * 12;

    const float* W = (z == 0) ? Wq : (z == 1) ? Wk : (z == 2) ? Wv : Wo;
    _Float16*   WT = (z == 0) ? WqT : (z == 1) ? WkT : (z == 2) ? WvT : WoT;
    const float scale = (z == 1) ? 0.125f * LOG2E : 1.0f;

    const int tx = threadIdx.x & 15, ty = threadIdx.x >> 4;
    const int n0 = bx * 64, k0 = by * 64;

    #pragma unroll
    for (int ii = 0; ii < 4; ++ii) {
        int k = ty + ii * 16;
        float4 v = *(const float4*)(W + (size_t)(k0 + k) * CC + n0 + tx * 4);
        tile[k][tx*4+0] = v.x; tile[k][tx*4+1] = v.y;
        tile[k][tx*4+2] = v.z; tile[k][tx*4+3] = v.w;
    }
    __syncthreads();
    #pragma unroll
    for (int ii = 0; ii < 4; ++ii) {
        int nn = ty + ii * 16;
        _Float16* dst = WT + (size_t)(n0 + nn) * CC + k0 + tx * 4;
        dst[0] = (_Float16)(tile[tx*4+0][nn] * scale);
        dst[1] = (_Float16)(tile[tx*4+1][nn] * scale);
        dst[2] = (_Float16)(tile[tx*4+2][nn] * scale);
        dst[3] = (_Float16)(tile[tx*4+3][nn] * scale);
    }
}

// ---------------------------------------------------------------------------
// Fused QKV GEMM (unchanged from R5: global_load_lds staging, XCD swizzle).
// ---------------------------------------------------------------------------
__global__ __launch_bounds__(256) void gemm_qkv3(
    const _Float16* __restrict__ xh, const _Float16* __restrict__ ch,
    const _Float16* __restrict__ WqT, const _Float16* __restrict__ WkT,
    const _Float16* __restrict__ WvT,
    _Float16* __restrict__ Qh, _Float16* __restrict__ Kh,
    _Float16* __restrict__ Vt)
{
    const int bid = blockIdx.x;
    const int lid = (bid & 7) * 144 + (bid >> 3);
    const int z   = lid / 384;
    const int rem = lid - z * 384;
    const int by  = rem / 6;
    const int bx  = rem - by * 6;

    const _Float16* A  = (z == 0) ? xh : ch;
    const _Float16* BT = (z == 0) ? WqT : (z == 1) ? WkT : WvT;

    __shared__ _Float16 smem[128 * 137];
    _Float16* sA = smem;
    _Float16* sB = smem + 128 * 64;

    const int tid  = threadIdx.x;
    const int wave = tid >> 6, lane = tid & 63;
    const int quad = lane >> 4, l16 = lane & 15;
    const int m0 = by * 128, n0 = bx * 128;
    const int mw = (wave & 1) * 64, nw = (wave >> 1) * 64;

    const int srow = wave * 32 + (lane >> 3);
    const int scol = (lane & 7) * 8;

    f32x4 acc[4][4];
    #pragma unroll
    for (int i = 0; i < 4; ++i)
        #pragma unroll
        for (int j = 0; j < 4; ++j) acc[i][j] = (f32x4){0.f,0.f,0.f,0.f};

    for (int kt = 0; kt < CC; kt += 64) {
        #pragma unroll
        for (int i = 0; i < 4; ++i) {
            gload_lds16(A  + (size_t)(m0 + srow + i*8) * CC + kt + scol,
                        &sA[(wave*32 + i*8) * 64]);
            gload_lds16(BT + (size_t)(n0 + srow + i*8) * CC + kt + scol,
                        &sB[(wave*32 + i*8) * 64]);
        }
        __syncthreads();
        #pragma unroll
        for (int kk = 0; kk < 2; ++kk) {
            hv8 af[4], bf[4];
            #pragma unroll
            for (int mi = 0; mi < 4; ++mi)
                af[mi] = *(const hv8*)&sA[(mw + mi*16 + l16)*64 + kk*32 + quad*8];
            #pragma unroll
            for (int nj = 0; nj < 4; ++nj)
                bf[nj] = *(const hv8*)&sB[(nw + nj*16 + l16)*64 + kk*32 + quad*8];
            #pragma unroll
            for (int mi = 0; mi < 4; ++mi)
                #pragma unroll
                for (int nj = 0; nj < 4; ++nj)
                    acc[mi][nj] = __builtin_amdgcn_mfma_f32_16x16x32_f16(
                        af[mi], bf[nj], acc[mi][nj], 0, 0, 0);
        }
        __syncthreads();
    }

    if (z < 2) {
        _Float16* Chead = (z == 0) ? Qh : Kh;
        _Float16* sT = smem;   // [128][137]
        #pragma unroll
        for (int mi = 0; mi < 4; ++mi)
            #pragma unroll
            for (int nj = 0; nj < 4; ++nj)
                #pragma unroll
                for (int r = 0; r < 4; ++r)
                    sT[(mw + mi*16 + quad*4 + r)*137 + nw + nj*16 + l16] =
                        (_Float16)acc[mi][nj][r];
        __syncthreads();
        #pragma unroll
        for (int ii = 0; ii < 8; ++ii) {
            int u = tid + ii * 256;
            int row = u >> 4;
            int chk = u & 15;
            hv8 o;
            #pragma unroll
            for (int j = 0; j < 8; ++j) o[j] = sT[row*137 + chk*8 + j];
            int gm = m0 + row, gn = n0 + chk*8;
            int bI = gm >> 10, tI = gm & 1023;
            int hI = gn >> 6,  dI = gn & 63;
            *(hv8*)(Chead + (((size_t)bI * NH + hI) * TT + tI) * HD + dI) = o;
        }
    } else {
        _Float16* sT = smem;   // [128][137]
        #pragma unroll
        for (int mi = 0; mi < 4; ++mi)
            #pragma unroll
            for (int nj = 0; nj < 4; ++nj)
                #pragma unroll
                for (int r = 0; r < 4; ++r)
                    sT[(mw + mi*16 + quad*4 + r)*137 + nw + nj*16 + l16] =
                        (_Float16)acc[mi][nj][r];
        __syncthreads();
        #pragma unroll
        for (int ii = 0; ii < 8; ++ii) {
            int u = tid + ii * 256;
            int dloc = u >> 4;
            int tch  = u & 15;
            hv8 o;
            #pragma unroll
            for (int j = 0; j < 8; ++j) o[j] = sT[(tch*8 + j)*137 + dloc];
            int gn = n0 + dloc;
            int hI = gn >> 6, dI = gn & 63;
            int gm = m0 + tch * 8;
            int bI = gm >> 10, tI = gm & 1023;
            *(hv8*)(Vt + (((size_t)bI * NH + hI) * HD + dI) * TT + tI) = o;
        }
    }
}

// ---------------------------------------------------------------------------
// fp16 single-pass output GEMM (unchanged from R5).
// ---------------------------------------------------------------------------
__global__ __launch_bounds__(256) void gemm_out_f16(
    const _Float16* __restrict__ A, const _Float16* __restrict__ BT,
    const float* __restrict__ bias, float* __restrict__ out)
{
    __shared__ _Float16 sA[128 * 64];
    __shared__ _Float16 sB[64 * 64];

    const int bid = blockIdx.x;
    const int lid = (bid & 7) * 96 + (bid >> 3);
    const int by  = lid / 12;
    const int bx  = lid - by * 12;

    const int tid  = threadIdx.x;
    const int wave = tid >> 6, lane = tid & 63;
    const int quad = lane >> 4, l16 = lane & 15;
    const int m0 = by * 128, n0 = bx * 64;
    const int mw = (wave & 1) * 64, nw = (wave >> 1) * 32;

    const int srow = lane >> 3;
    const int scol = (lane & 7) * 8;

    f32x4 acc[4][2];
    #pragma unroll
    for (int i = 0; i < 4; ++i)
        #pragma unroll
        for (int j = 0; j < 2; ++j) acc[i][j] = (f32x4){0.f,0.f,0.f,0.f};

    for (int kt = 0; kt < CC; kt += 64) {
        #pragma unroll
        for (int i = 0; i < 4; ++i)
            gload_lds16(A + (size_t)(m0 + wave*32 + i*8 + srow) * CC + kt + scol,
                        &sA[(wave*32 + i*8) * 64]);
        #pragma unroll
        for (int i = 0; i < 2; ++i)
            gload_lds16(BT + (size_t)(n0 + wave*16 + i*8 + srow) * CC + kt + scol,
                        &sB[(wave*16 + i*8) * 64]);
        __syncthreads();
        #pragma unroll
        for (int kk = 0; kk < 2; ++kk) {
            hv8 af[4], bf[2];
            #pragma unroll
            for (int mi = 0; mi < 4; ++mi)
                af[mi] = *(const hv8*)&sA[(mw + mi*16 + l16)*64 + kk*32 + quad*8];
            #pragma unroll
            for (int nj = 0; nj < 2; ++nj)
                bf[nj] = *(const hv8*)&sB[(nw + nj*16 + l16)*64 + kk*32 + quad*8];
            #pragma unroll
            for (int mi = 0; mi < 4; ++mi)
                #pragma unroll
                for (int nj = 0; nj < 2; ++nj)
                    acc[mi][nj] = __builtin_amdgcn_mfma_f32_16x16x32_f16(
                        af[mi], bf[nj], acc[mi][nj], 0, 0, 0);
        }
        __syncthreads();
    }

    #pragma unroll
    for (int mi = 0; mi < 4; ++mi)
        #pragma unroll
        for (int nj = 0; nj < 2; ++nj)
            #pragma unroll
            for (int r = 0; r < 4; ++r) {
                int gm = m0 + mw + mi*16 + quad*4 + r;
                int gn = n0 + nw + nj*16 + l16;
                out[(size_t)gm * CC + gn] = acc[mi][nj][r] + bias[gn];
            }
}

// ---------------------------------------------------------------------------
// fp16 MFMA flash attention, BQ=128, R7 STRUCTURAL REWRITE:
//   * swapped QK^T (mfma(K,Q) -> S^T): lane (l16,quad) reg r holds
//     P[q=g*16+l16][k=bb*16+quad*4+r] -- which is EXACTLY the A-fragment
//     layout of mfma_f32_16x16x16f16 -> PV and row-sum consume P directly
//     from registers.  The entire sP LDS round-trip (32 ds_write + lgkm +
//     8 ds_read_b128 per kt) is GONE.
//   * freed 18.4KB -> K/V double-buffered in the same 45.5KB footprint ->
//     ONE barrier per kt (was 2); staging writes overlap compute on the
//     other buffer (T14 kept: global->reg issued 2 tiles ahead).
//   * bias via C-init: c[r] = rh[q][kt*2+(bb>>1)] + G[q][q32-kw+31], with
//     rh now lane-constant per g (2 b32 reads/kt).
// Output fragment layouts of PV/rowsum (D[m=quad*4+r][n=l16]) match the old
// o/lacc layouts exactly -> finalize unchanged.
// ---------------------------------------------------------------------------
#define KOFFB(b) ((b)*9216)          // K tile of buf b (halves)
#define VOFFB(b) ((b)*9216 + 4608)   // V tile of buf b

__global__ __launch_bounds__(256) void attn_mfma(
    const _Float16* __restrict__ Q, const _Float16* __restrict__ K,
    const _Float16* __restrict__ Vt, const float* __restrict__ relh,
    const float* __restrict__ relw, _Float16* __restrict__ O)
{
    // 2 dbuf x {K[64][72], V[64][72]} = 18432 halves.
    // Prologue overlays: Q(128x72) -> buf0 K+V; relh(35x72) -> buf1 K;
    // relw(64x72) -> buf1 V; per-wave G(32x72) -> buf0 (after aQ extract).
    __shared__ _Float16 sKV[18432];
    __shared__ _Float16 sH [128][34];   // rh table [qi][hk]

    const int tid  = threadIdx.x;
    const int wave = tid >> 6, lane = tid & 63;
    const int quad = lane >> 4, l16 = lane & 15;

    // T1 swizzle: all 8 q-tiles of one (b,h) on one XCD (K/V L2-local).
    const int bid = blockIdx.x;
    const int idx = bid >> 3;
    const int qt  = idx & 7;
    const int bh  = (bid & 7) + 8 * (idx >> 3);
    const int h   = bh % NH;
    const int b   = bh / NH;
    const size_t hbase = ((size_t)b * NH + h) * TT * HD;

    // ---- K/V tile prefetch registers (async staging, 1 reg set)
    short8 pK[2], pV[2];
    auto loadKV = [&](int kt) {
        #pragma unroll
        for (int ii = 0; ii < 2; ++ii) {
            int u = tid + ii * 256;
            int row = u >> 3, c8 = u & 7;
            pK[ii] = *(const short8*)(K  + hbase + (size_t)(kt*64 + row) * HD + c8*8);
            pV[ii] = *(const short8*)(Vt + hbase + (size_t)row * TT + kt*64 + c8*8);
        }
    };
    auto writeKV = [&](int bf) {
        #pragma unroll
        for (int ii = 0; ii < 2; ++ii) {
            int u = tid + ii * 256;
            int row = u >> 3, c8 = u & 7;
            *(short8*)&sKV[KOFFB(bf) + row*72 + c8*8] = pK[ii];
            *(short8*)&sKV[VOFFB(bf) + row*72 + c8*8] = pV[ii];
        }
    };

    // ---- prologue staging: Q -> buf0 region, relh -> buf1-K, relw -> buf1-V
    #pragma unroll
    for (int ii = 0; ii < 4; ++ii) {
        int u = tid + ii * 256;
        int row = u >> 3, c8 = u & 7;
        *(short8*)&sKV[row*72 + c8*8] =
            *(const short8*)(Q + hbase + (size_t)(qt*128 + row) * HD + c8*8);
    }
    #pragma unroll
    for (int ii = 0; ii < 2; ++ii) {
        int u = tid + ii * 256;
        if (u < 280) {                 // 35 rows x 8 chunks of relh window
            int row = u >> 3, c8 = u & 7;
            const float* src = relh + (size_t)(4*qt + row) * HD + c8*8;
            float4 v0 = *(const float4*)(src);
            float4 v1 = *(const float4*)(src + 4);
            hv8 s = { (_Float16)(v0.x*LOG2E), (_Float16)(v0.y*LOG2E),
                      (_Float16)(v0.z*LOG2E), (_Float16)(v0.w*LOG2E),
                      (_Float16)(v1.x*LOG2E), (_Float16)(v1.y*LOG2E),
                      (_Float16)(v1.z*LOG2E), (_Float16)(v1.w*LOG2E) };
            *(hv8*)&sKV[9216 + row*72 + c8*8] = s;
        }
    }
    #pragma unroll
    for (int ii = 0; ii < 2; ++ii) {
        int u = tid + ii * 256;
        int row = u >> 3, c8 = u & 7;
        int sr = row < 63 ? row : 62;
        const float* src = relw + (size_t)sr * HD + c8*8;
        float4 v0 = *(const float4*)(src);
        float4 v1 = *(const float4*)(src + 4);
        hv8 s = { (_Float16)(v0.x*LOG2E), (_Float16)(v0.y*LOG2E),
                  (_Float16)(v0.z*LOG2E), (_Float16)(v0.w*LOG2E),
                  (_Float16)(v1.x*LOG2E), (_Float16)(v1.y*LOG2E),
                  (_Float16)(v1.z*LOG2E), (_Float16)(v1.w*LOG2E) };
        *(hv8*)&sKV[13824 + row*72 + c8*8] = s;
    }
    loadKV(0);                         // k-tile 0 in flight during prologue math
    __syncthreads();

    // ---- persistent Q A-fragments
    hv8 aQ0[2], aQ1[2];
    #pragma unroll
    for (int g = 0; g < 2; ++g) {
        int qrow = wave*32 + g*16 + l16;
        aQ0[g] = *(const hv8*)&sKV[qrow*72 + quad*8];
        aQ1[g] = *(const hv8*)&sKV[qrow*72 + 32 + quad*8];
    }
    __syncthreads();   // aQ loaded before G-writes clobber the Q overlay

    // ---- RH via MFMA (unswapped): sH[qi][hk] = q . relh[hq-hk+31]
    #pragma unroll
    for (int g = 0; g < 2; ++g)
        #pragma unroll
        for (int t = 0; t < 2; ++t) {
            int wr = wave + 31 - (t*16 + l16);
            hv8 b0 = *(const hv8*)&sKV[9216 + wr*72 + quad*8];
            hv8 b1 = *(const hv8*)&sKV[9216 + wr*72 + 32 + quad*8];
            f32x4 c = {0.f,0.f,0.f,0.f};
            c = __builtin_amdgcn_mfma_f32_16x16x32_f16(aQ0[g], b0, c, 0, 0, 0);
            c = __builtin_amdgcn_mfma_f32_16x16x32_f16(aQ1[g], b1, c, 0, 0, 0);
            #pragma unroll
            for (int r = 0; r < 4; ++r)
                sH[wave*32 + g*16 + quad*4 + r][t*16 + l16] = (_Float16)c[r];
        }
    // ---- G = Q @ relw^T (unswapped) into own-wave region over the Q overlay
    #pragma unroll
    for (int g = 0; g < 2; ++g)
        #pragma unroll
        for (int t = 0; t < 4; ++t) {
            hv8 b0 = *(const hv8*)&sKV[13824 + (t*16 + l16)*72 + quad*8];
            hv8 b1 = *(const hv8*)&sKV[13824 + (t*16 + l16)*72 + 32 + quad*8];
            f32x4 c = {0.f,0.f,0.f,0.f};
            c = __builtin_amdgcn_mfma_f32_16x16x32_f16(aQ0[g], b0, c, 0, 0, 0);
            c = __builtin_amdgcn_mfma_f32_16x16x32_f16(aQ1[g], b1, c, 0, 0, 0);
            #pragma unroll
            for (int r = 0; r < 4; ++r)
                sKV[wave*2304 + (g*16 + quad*4 + r)*72 + t*16 + l16] = (_Float16)c[r];
        }
    // ---- gather RW bias for the SWAPPED consumer layout:
    //      rwSw[g][j][r] = G[q=g*16+l16][ (g*16+l16) - j*16 - quad*4 - r + 31 ]
    //      (same-wave LDS, write->read ordered by lgkmcnt)
    float rwSw[2][2][4];
    #pragma unroll
    for (int g = 0; g < 2; ++g)
        #pragma unroll
        for (int j = 0; j < 2; ++j)
            #pragma unroll
            for (int r = 0; r < 4; ++r) {
                int q32 = g*16 + l16;
                int w   = q32 - j*16 - quad*4 - r + 31;   // 0..62
                rwSw[g][j][r] = (float)sKV[wave*2304 + q32*72 + w];
            }
    __syncthreads();   // G consumed; buf0 region free
    writeKV(0);        // k-tile 0 -> buf0
    loadKV(1);
    __syncthreads();   // buf0 ready

    f32x4 o[2][4];
    #pragma unroll
    for (int g = 0; g < 2; ++g)
        #pragma unroll
        for (int n = 0; n < 4; ++n) o[g][n] = (f32x4){0.f,0.f,0.f,0.f};
    f32x4 lacc[2] = { (f32x4){0.f,0.f,0.f,0.f}, (f32x4){0.f,0.f,0.f,0.f} };
    const hv4 vone4 = { (_Float16)1.f, (_Float16)1.f, (_Float16)1.f, (_Float16)1.f };

    for (int kt = 0; kt < 16; ++kt) {
        const int buf = kt & 1;
        // stage tile kt+1 into the other buffer (readers of it synced out
        // by the end-of-(kt-1) barrier); issue loads for kt+2.
        if (kt < 15) writeKV(buf ^ 1);
        if (kt < 14) loadKV(kt + 2);

        // ---- rh bias: lane-constant per g (2 x b32)
        float rhq[2][2];
        #pragma unroll
        for (int g = 0; g < 2; ++g) {
            unsigned pr = *(const unsigned*)&sH[wave*32 + g*16 + l16][kt*2];
            rhq[g][0] = (float)(*(const _Float16*)&pr);
            rhq[g][1] = (float)(*((const _Float16*)&pr + 1));
        }

        // ---- swapped QK^T: S^T = mfma(K, Q, bias); exp2; pack to hv4.
        //      lane reg r ends up as P[q=g*16+l16][k=bb*16+quad*4+r]
        hv4 pk[2][4];
        #pragma unroll
        for (int bb = 0; bb < 4; ++bb) {
            hv8 bK0 = *(const hv8*)&sKV[KOFFB(buf) + (bb*16 + l16)*72 + quad*8];
            hv8 bK1 = *(const hv8*)&sKV[KOFFB(buf) + (bb*16 + l16)*72 + 32 + quad*8];
            #pragma unroll
            for (int g = 0; g < 2; ++g) {
                f32x4 c;
                #pragma unroll
                for (int r = 0; r < 4; ++r)
                    c[r] = rhq[g][bb>>1] + rwSw[g][bb&1][r];
                c = __builtin_amdgcn_mfma_f32_16x16x32_f16(bK0, aQ0[g], c, 0, 0, 0);
                c = __builtin_amdgcn_mfma_f32_16x16x32_f16(bK1, aQ1[g], c, 0, 0, 0);
                hv4 t;
                #pragma unroll
                for (int r = 0; r < 4; ++r) t[r] = (_Float16)fast_exp2(c[r]);
                pk[g][bb] = t;
            }
        }

        __builtin_amdgcn_s_setprio(1);
        // ---- row-sum: lacc += P_bb @ ones (K=16 MFMA, P straight from regs)
        #pragma unroll
        for (int g = 0; g < 2; ++g)
            #pragma unroll
            for (int bb = 0; bb < 4; ++bb)
                lacc[g] = __builtin_amdgcn_mfma_f32_16x16x16f16(
                    pk[g][bb], vone4, lacc[g], 0, 0, 0);
        // ---- O += P @ V  (K=16 MFMAs; bV = V[k=bb*16+quad*4..+3][d=nn*16+l16])
        #pragma unroll
        for (int nn = 0; nn < 4; ++nn)
            #pragma unroll
            for (int bb = 0; bb < 4; ++bb) {
                hv4 bV = *(const hv4*)&sKV[VOFFB(buf) + (nn*16 + l16)*72 + bb*16 + quad*4];
                #pragma unroll
                for (int g = 0; g < 2; ++g)
                    o[g][nn] = __builtin_amdgcn_mfma_f32_16x16x16f16(
                        pk[g][bb], bV, o[g][nn], 0, 0, 0);
            }
        __builtin_amdgcn_s_setprio(0);

        __syncthreads();               // tile kt consumed; tile kt+1 visible
    }

    // ---- finalize: /l, fp16 out into [b, t, C]  (layouts unchanged)
    #pragma unroll
    for (int g = 0; g < 2; ++g) {
        float inv[4];
        #pragma unroll
        for (int r = 0; r < 4; ++r) inv[r] = 1.f / lacc[g][r];
        #pragma unroll
        for (int n = 0; n < 4; ++n)
            #pragma unroll
            for (int r = 0; r < 4; ++r) {
                int t = qt*128 + wave*32 + g*16 + quad*4 + r;
                size_t addr = ((size_t)b * TT + t) * CC + h*HD + n*16 + l16;
                O[addr] = (_Float16)(o[g][n][r] * inv[r]);
            }
    }
}

// ---------------------------------------------------------------------------
extern "C" void kernel_launch(void* const* d_in, const int* in_sizes, int n_in,
                              void* d_out, int out_size, void* d_ws, size_t ws_size,
                              hipStream_t stream) {
    const float* x   = (const float*)d_in[0];
    const float* ctx = (const float*)d_in[1];
    const float* Wq  = (const float*)d_in[2];
    const float* Wk  = (const float*)d_in[3];
    const float* Wv  = (const float*)d_in[4];
    const float* Wo  = (const float*)d_in[5];
    const float* bo  = (const float*)d_in[6];
    const float* rh  = (const float*)d_in[7];
    const float* rw  = (const float*)d_in[8];
    float* out = (float*)d_out;

    const size_t MN = (size_t)BB * TT * CC;   // 6291456
    const size_t WN = (size_t)CC * CC;        // 589824
    _Float16* p = (_Float16*)d_ws;
    _Float16* xh  = p; p += MN;
    _Float16* ch  = p; p += MN;
    _Float16* WqT = p; p += WN;
    _Float16* WkT = p; p += WN;
    _Float16* WvT = p; p += WN;
    _Float16* WoT = p; p += WN;
    _Float16* Qh  = p; p += MN;
    _Float16* Kh  = p; p += MN;
    _Float16* VtB = p; p += MN;
    _Float16* Oh  = p; p += MN;

    dim3 blk(256);

    prep_fused<<<dim3(6720), blk, 0, stream>>>(
        x, ctx, xh, ch, (int)MN, Wq, Wk, Wv, Wo, WqT, WkT, WvT, WoT);

    gemm_qkv3<<<dim3(1152), blk, 0, stream>>>(
        xh, ch, WqT, WkT, WvT, Qh, Kh, VtB);

    attn_mfma<<<dim3(BB*NH*(TT/128)), blk, 0, stream>>>(
        Qh, Kh, VtB, rh, rw, Oh);

    gemm_out_f16<<<dim3(768), blk, 0, stream>>>(
        Oh, WoT, bo, out);
}

// Round 8
// 220.741 us; speedup vs baseline: 1.0874x; 1.0874x over previous
//
#include <hip/hip_runtime.h>
#include <math.h>

#define BB 8
#define TT 1024
#define CC 768
#define NH 12
#define HD 64
#define LOG2E 1.44269504088896f

typedef __attribute__((ext_vector_type(8))) _Float16 hv8;   // 8 fp16 (4 VGPRs)
typedef __attribute__((ext_vector_type(8))) short  short8;  // raw 16B
typedef __attribute__((ext_vector_type(4))) float  f32x4;

static __device__ __forceinline__ float fast_exp2(float x) {
#if __has_builtin(__builtin_amdgcn_exp2f)
    return __builtin_amdgcn_exp2f(x);
#else
    return exp2f(x);
#endif
}

// Async global->LDS DMA, 16B per lane (global_load_lds_dwordx4).
static __device__ __forceinline__ void gload_lds16(
    const _Float16* __restrict__ g, _Float16* l)
{
    __builtin_amdgcn_global_load_lds(
        (const __attribute__((address_space(1))) void*)g,
        (__attribute__((address_space(3))) void*)l, 16, 0, 0);
}

// ---------------------------------------------------------------------------
// Fused prep -- fp32->fp16 convert of x/ctx (blocks 0..6143) AND the 4
// weight transposes (blocks 6144..6719).  Wk carries 0.125*log2e.
// ---------------------------------------------------------------------------
__global__ __launch_bounds__(256) void prep_fused(
    const float* __restrict__ x, const float* __restrict__ ctx,
    _Float16* __restrict__ xh, _Float16* __restrict__ ch, int n,
    const float* __restrict__ Wq, const float* __restrict__ Wk,
    const float* __restrict__ Wv, const float* __restrict__ Wo,
    _Float16* __restrict__ WqT, _Float16* __restrict__ WkT,
    _Float16* __restrict__ WvT, _Float16* __restrict__ WoT)
{
    __shared__ float tile[64][65];
    const int bid = blockIdx.x;

    if (bid < 6144) {
        const float* in = (bid >= 3072) ? ctx : x;
        _Float16* out   = (bid >= 3072) ? ch  : xh;
        int bb2 = (bid >= 3072) ? bid - 3072 : bid;
        int i = (bb2 * 256 + threadIdx.x) * 8;
        if (i < n) {
            float4 v0 = *(const float4*)(in + i);
            float4 v1 = *(const float4*)(in + i + 4);
            hv8 h = { (_Float16)v0.x, (_Float16)v0.y, (_Float16)v0.z, (_Float16)v0.w,
                      (_Float16)v1.x, (_Float16)v1.y, (_Float16)v1.z, (_Float16)v1.w };
            *(hv8*)(out + i) = h;
        }
        return;
    }

    const int t  = bid - 6144;            // 0..575
    const int z  = t / 144;
    const int rm = t - z * 144;
    const int by = rm / 12, bx = rm - by * 12;

    const float* W = (z == 0) ? Wq : (z == 1) ? Wk : (z == 2) ? Wv : Wo;
    _Float16*   WT = (z == 0) ? WqT : (z == 1) ? WkT : (z == 2) ? WvT : WoT;
    const float scale = (z == 1) ? 0.125f * LOG2E : 1.0f;

    const int tx = threadIdx.x & 15, ty = threadIdx.x >> 4;
    const int n0 = bx * 64, k0 = by * 64;

    #pragma unroll
    for (int ii = 0; ii < 4; ++ii) {
        int k = ty + ii * 16;
        float4 v = *(const float4*)(W + (size_t)(k0 + k) * CC + n0 + tx * 4);
        tile[k][tx*4+0] = v.x; tile[k][tx*4+1] = v.y;
        tile[k][tx*4+2] = v.z; tile[k][tx*4+3] = v.w;
    }
    __syncthreads();
    #pragma unroll
    for (int ii = 0; ii < 4; ++ii) {
        int nn = ty + ii * 16;
        _Float16* dst = WT + (size_t)(n0 + nn) * CC + k0 + tx * 4;
        dst[0] = (_Float16)(tile[tx*4+0][nn] * scale);
        dst[1] = (_Float16)(tile[tx*4+1][nn] * scale);
        dst[2] = (_Float16)(tile[tx*4+2][nn] * scale);
        dst[3] = (_Float16)(tile[tx*4+3][nn] * scale);
    }
}

// ---------------------------------------------------------------------------
// Fused QKV GEMM (unchanged from R5: global_load_lds staging, XCD swizzle).
// ---------------------------------------------------------------------------
__global__ __launch_bounds__(256) void gemm_qkv3(
    const _Float16* __restrict__ xh, const _Float16* __restrict__ ch,
    const _Float16* __restrict__ WqT, const _Float16* __restrict__ WkT,
    const _Float16* __restrict__ WvT,
    _Float16* __restrict__ Qh, _Float16* __restrict__ Kh,
    _Float16* __restrict__ Vt)
{
    const int bid = blockIdx.x;
    const int lid = (bid & 7) * 144 + (bid >> 3);
    const int z   = lid / 384;
    const int rem = lid - z * 384;
    const int by  = rem / 6;
    const int bx  = rem - by * 6;

    const _Float16* A  = (z == 0) ? xh : ch;
    const _Float16* BT = (z == 0) ? WqT : (z == 1) ? WkT : WvT;

    __shared__ _Float16 smem[128 * 137];
    _Float16* sA = smem;
    _Float16* sB = smem + 128 * 64;

    const int tid  = threadIdx.x;
    const int wave = tid >> 6, lane = tid & 63;
    const int quad = lane >> 4, l16 = lane & 15;
    const int m0 = by * 128, n0 = bx * 128;
    const int mw = (wave & 1) * 64, nw = (wave >> 1) * 64;

    const int srow = wave * 32 + (lane >> 3);
    const int scol = (lane & 7) * 8;

    f32x4 acc[4][4];
    #pragma unroll
    for (int i = 0; i < 4; ++i)
        #pragma unroll
        for (int j = 0; j < 4; ++j) acc[i][j] = (f32x4){0.f,0.f,0.f,0.f};

    for (int kt = 0; kt < CC; kt += 64) {
        #pragma unroll
        for (int i = 0; i < 4; ++i) {
            gload_lds16(A  + (size_t)(m0 + srow + i*8) * CC + kt + scol,
                        &sA[(wave*32 + i*8) * 64]);
            gload_lds16(BT + (size_t)(n0 + srow + i*8) * CC + kt + scol,
                        &sB[(wave*32 + i*8) * 64]);
        }
        __syncthreads();
        #pragma unroll
        for (int kk = 0; kk < 2; ++kk) {
            hv8 af[4], bf[4];
            #pragma unroll
            for (int mi = 0; mi < 4; ++mi)
                af[mi] = *(const hv8*)&sA[(mw + mi*16 + l16)*64 + kk*32 + quad*8];
            #pragma unroll
            for (int nj = 0; nj < 4; ++nj)
                bf[nj] = *(const hv8*)&sB[(nw + nj*16 + l16)*64 + kk*32 + quad*8];
            #pragma unroll
            for (int mi = 0; mi < 4; ++mi)
                #pragma unroll
                for (int nj = 0; nj < 4; ++nj)
                    acc[mi][nj] = __builtin_amdgcn_mfma_f32_16x16x32_f16(
                        af[mi], bf[nj], acc[mi][nj], 0, 0, 0);
        }
        __syncthreads();
    }

    if (z < 2) {
        _Float16* Chead = (z == 0) ? Qh : Kh;
        _Float16* sT = smem;   // [128][137]
        #pragma unroll
        for (int mi = 0; mi < 4; ++mi)
            #pragma unroll
            for (int nj = 0; nj < 4; ++nj)
                #pragma unroll
                for (int r = 0; r < 4; ++r)
                    sT[(mw + mi*16 + quad*4 + r)*137 + nw + nj*16 + l16] =
                        (_Float16)acc[mi][nj][r];
        __syncthreads();
        #pragma unroll
        for (int ii = 0; ii < 8; ++ii) {
            int u = tid + ii * 256;
            int row = u >> 4;
            int chk = u & 15;
            hv8 o;
            #pragma unroll
            for (int j = 0; j < 8; ++j) o[j] = sT[row*137 + chk*8 + j];
            int gm = m0 + row, gn = n0 + chk*8;
            int bI = gm >> 10, tI = gm & 1023;
            int hI = gn >> 6,  dI = gn & 63;
            *(hv8*)(Chead + (((size_t)bI * NH + hI) * TT + tI) * HD + dI) = o;
        }
    } else {
        _Float16* sT = smem;   // [128][137]
        #pragma unroll
        for (int mi = 0; mi < 4; ++mi)
            #pragma unroll
            for (int nj = 0; nj < 4; ++nj)
                #pragma unroll
                for (int r = 0; r < 4; ++r)
                    sT[(mw + mi*16 + quad*4 + r)*137 + nw + nj*16 + l16] =
                        (_Float16)acc[mi][nj][r];
        __syncthreads();
        #pragma unroll
        for (int ii = 0; ii < 8; ++ii) {
            int u = tid + ii * 256;
            int dloc = u >> 4;
            int tch  = u & 15;
            hv8 o;
            #pragma unroll
            for (int j = 0; j < 8; ++j) o[j] = sT[(tch*8 + j)*137 + dloc];
            int gn = n0 + dloc;
            int hI = gn >> 6, dI = gn & 63;
            int gm = m0 + tch * 8;
            int bI = gm >> 10, tI = gm & 1023;
            *(hv8*)(Vt + (((size_t)bI * NH + hI) * HD + dI) * TT + tI) = o;
        }
    }
}

// ---------------------------------------------------------------------------
// fp16 single-pass output GEMM (unchanged from R5).
// ---------------------------------------------------------------------------
__global__ __launch_bounds__(256) void gemm_out_f16(
    const _Float16* __restrict__ A, const _Float16* __restrict__ BT,
    const float* __restrict__ bias, float* __restrict__ out)
{
    __shared__ _Float16 sA[128 * 64];
    __shared__ _Float16 sB[64 * 64];

    const int bid = blockIdx.x;
    const int lid = (bid & 7) * 96 + (bid >> 3);
    const int by  = lid / 12;
    const int bx  = lid - by * 12;

    const int tid  = threadIdx.x;
    const int wave = tid >> 6, lane = tid & 63;
    const int quad = lane >> 4, l16 = lane & 15;
    const int m0 = by * 128, n0 = bx * 64;
    const int mw = (wave & 1) * 64, nw = (wave >> 1) * 32;

    const int srow = lane >> 3;
    const int scol = (lane & 7) * 8;

    f32x4 acc[4][2];
    #pragma unroll
    for (int i = 0; i < 4; ++i)
        #pragma unroll
        for (int j = 0; j < 2; ++j) acc[i][j] = (f32x4){0.f,0.f,0.f,0.f};

    for (int kt = 0; kt < CC; kt += 64) {
        #pragma unroll
        for (int i = 0; i < 4; ++i)
            gload_lds16(A + (size_t)(m0 + wave*32 + i*8 + srow) * CC + kt + scol,
                        &sA[(wave*32 + i*8) * 64]);
        #pragma unroll
        for (int i = 0; i < 2; ++i)
            gload_lds16(BT + (size_t)(n0 + wave*16 + i*8 + srow) * CC + kt + scol,
                        &sB[(wave*16 + i*8) * 64]);
        __syncthreads();
        #pragma unroll
        for (int kk = 0; kk < 2; ++kk) {
            hv8 af[4], bf[2];
            #pragma unroll
            for (int mi = 0; mi < 4; ++mi)
                af[mi] = *(const hv8*)&sA[(mw + mi*16 + l16)*64 + kk*32 + quad*8];
            #pragma unroll
            for (int nj = 0; nj < 2; ++nj)
                bf[nj] = *(const hv8*)&sB[(nw + nj*16 + l16)*64 + kk*32 + quad*8];
            #pragma unroll
            for (int mi = 0; mi < 4; ++mi)
                #pragma unroll
                for (int nj = 0; nj < 2; ++nj)
                    acc[mi][nj] = __builtin_amdgcn_mfma_f32_16x16x32_f16(
                        af[mi], bf[nj], acc[mi][nj], 0, 0, 0);
        }
        __syncthreads();
    }

    #pragma unroll
    for (int mi = 0; mi < 4; ++mi)
        #pragma unroll
        for (int nj = 0; nj < 2; ++nj)
            #pragma unroll
            for (int r = 0; r < 4; ++r) {
                int gm = m0 + mw + mi*16 + quad*4 + r;
                int gn = n0 + nw + nj*16 + l16;
                out[(size_t)gm * CC + gn] = acc[mi][nj][r] + bias[gn];
            }
}

// ---------------------------------------------------------------------------
// fp16 MFMA flash attention, BQ=128.  R8 = R7 structure (swapped QK^T,
// register-resident P, K/V double-buffer, 1 barrier/kt) + PERMLANE REPACK:
//   R7's mistake: PV/rowsum via 16x16x16 MFMA -- on CDNA4 K=16 costs the
//   SAME cycles as K=32 (the 2xK instrs double FLOPs at constant cycles),
//   so PV pipe cost doubled (MfmaUtil 17.9->28.7 for identical FLOPs).
//   Fix: repack S^T fragments (lane holds k=bb*16+quad*4+r, 4-contiguous-k
//   runs) into K=32 A-fragments (k=quad*8+j) IN REGISTERS:
//     per (kk,rr): e=pack(bb=2kk), o=pack(bb=2kk+1)
//     v_permlane32_swap(e,o): e=(e0,e1,o0,o1) o=(e2,e3,o2,o3)  [quad-space]
//     v_permlane16_swap(e,o): e=(e0,e2,o0,o2)=W(2rr) o=(e1,e3,o1,o3)=W(4+2rr)
//   16 permlane + 16 pack ops/kt replace both the LDS round-trip (R6) and
//   the 2x pipe cost (R7).  PV/rowsum back to 16+4 mfma_f32_16x16x32_f16.
// ---------------------------------------------------------------------------
#define KOFFB(b) ((b)*9216)          // K tile of buf b (halves)
#define VOFFB(b) ((b)*9216 + 4608)   // V tile of buf b

__global__ __launch_bounds__(256) void attn_mfma(
    const _Float16* __restrict__ Q, const _Float16* __restrict__ K,
    const _Float16* __restrict__ Vt, const float* __restrict__ relh,
    const float* __restrict__ relw, _Float16* __restrict__ O)
{
    __shared__ _Float16 sKV[18432];     // 2 dbuf x {K[64][72], V[64][72]}
    __shared__ _Float16 sH [128][34];   // rh table [qi][hk]

    const int tid  = threadIdx.x;
    const int wave = tid >> 6, lane = tid & 63;
    const int quad = lane >> 4, l16 = lane & 15;

    // T1 swizzle: all 8 q-tiles of one (b,h) on one XCD (K/V L2-local).
    const int bid = blockIdx.x;
    const int idx = bid >> 3;
    const int qt  = idx & 7;
    const int bh  = (bid & 7) + 8 * (idx >> 3);
    const int h   = bh % NH;
    const int b   = bh / NH;
    const size_t hbase = ((size_t)b * NH + h) * TT * HD;

    // ---- K/V tile prefetch registers (async staging, 1 reg set)
    short8 pK[2], pV[2];
    auto loadKV = [&](int kt) {
        #pragma unroll
        for (int ii = 0; ii < 2; ++ii) {
            int u = tid + ii * 256;
            int row = u >> 3, c8 = u & 7;
            pK[ii] = *(const short8*)(K  + hbase + (size_t)(kt*64 + row) * HD + c8*8);
            pV[ii] = *(const short8*)(Vt + hbase + (size_t)row * TT + kt*64 + c8*8);
        }
    };
    auto writeKV = [&](int bf) {
        #pragma unroll
        for (int ii = 0; ii < 2; ++ii) {
            int u = tid + ii * 256;
            int row = u >> 3, c8 = u & 7;
            *(short8*)&sKV[KOFFB(bf) + row*72 + c8*8] = pK[ii];
            *(short8*)&sKV[VOFFB(bf) + row*72 + c8*8] = pV[ii];
        }
    };

    // ---- prologue staging: Q -> buf0 region, relh -> buf1-K, relw -> buf1-V
    #pragma unroll
    for (int ii = 0; ii < 4; ++ii) {
        int u = tid + ii * 256;
        int row = u >> 3, c8 = u & 7;
        *(short8*)&sKV[row*72 + c8*8] =
            *(const short8*)(Q + hbase + (size_t)(qt*128 + row) * HD + c8*8);
    }
    #pragma unroll
    for (int ii = 0; ii < 2; ++ii) {
        int u = tid + ii * 256;
        if (u < 280) {                 // 35 rows x 8 chunks of relh window
            int row = u >> 3, c8 = u & 7;
            const float* src = relh + (size_t)(4*qt + row) * HD + c8*8;
            float4 v0 = *(const float4*)(src);
            float4 v1 = *(const float4*)(src + 4);
            hv8 s = { (_Float16)(v0.x*LOG2E), (_Float16)(v0.y*LOG2E),
                      (_Float16)(v0.z*LOG2E), (_Float16)(v0.w*LOG2E),
                      (_Float16)(v1.x*LOG2E), (_Float16)(v1.y*LOG2E),
                      (_Float16)(v1.z*LOG2E), (_Float16)(v1.w*LOG2E) };
            *(hv8*)&sKV[9216 + row*72 + c8*8] = s;
        }
    }
    #pragma unroll
    for (int ii = 0; ii < 2; ++ii) {
        int u = tid + ii * 256;
        int row = u >> 3, c8 = u & 7;
        int sr = row < 63 ? row : 62;
        const float* src = relw + (size_t)sr * HD + c8*8;
        float4 v0 = *(const float4*)(src);
        float4 v1 = *(const float4*)(src + 4);
        hv8 s = { (_Float16)(v0.x*LOG2E), (_Float16)(v0.y*LOG2E),
                  (_Float16)(v0.z*LOG2E), (_Float16)(v0.w*LOG2E),
                  (_Float16)(v1.x*LOG2E), (_Float16)(v1.y*LOG2E),
                  (_Float16)(v1.z*LOG2E), (_Float16)(v1.w*LOG2E) };
        *(hv8*)&sKV[13824 + row*72 + c8*8] = s;
    }
    loadKV(0);                         // k-tile 0 in flight during prologue math
    __syncthreads();

    // ---- persistent Q A-fragments
    hv8 aQ0[2], aQ1[2];
    #pragma unroll
    for (int g = 0; g < 2; ++g) {
        int qrow = wave*32 + g*16 + l16;
        aQ0[g] = *(const hv8*)&sKV[qrow*72 + quad*8];
        aQ1[g] = *(const hv8*)&sKV[qrow*72 + 32 + quad*8];
    }
    __syncthreads();   // aQ loaded before G-writes clobber the Q overlay

    // ---- RH via MFMA (unswapped): sH[qi][hk] = q . relh[hq-hk+31]
    #pragma unroll
    for (int g = 0; g < 2; ++g)
        #pragma unroll
        for (int t = 0; t < 2; ++t) {
            int wr = wave + 31 - (t*16 + l16);
            hv8 b0 = *(const hv8*)&sKV[9216 + wr*72 + quad*8];
            hv8 b1 = *(const hv8*)&sKV[9216 + wr*72 + 32 + quad*8];
            f32x4 c = {0.f,0.f,0.f,0.f};
            c = __builtin_amdgcn_mfma_f32_16x16x32_f16(aQ0[g], b0, c, 0, 0, 0);
            c = __builtin_amdgcn_mfma_f32_16x16x32_f16(aQ1[g], b1, c, 0, 0, 0);
            #pragma unroll
            for (int r = 0; r < 4; ++r)
                sH[wave*32 + g*16 + quad*4 + r][t*16 + l16] = (_Float16)c[r];
        }
    // ---- G = Q @ relw^T (unswapped) into own-wave region over the Q overlay
    #pragma unroll
    for (int g = 0; g < 2; ++g)
        #pragma unroll
        for (int t = 0; t < 4; ++t) {
            hv8 b0 = *(const hv8*)&sKV[13824 + (t*16 + l16)*72 + quad*8];
            hv8 b1 = *(const hv8*)&sKV[13824 + (t*16 + l16)*72 + 32 + quad*8];
            f32x4 c = {0.f,0.f,0.f,0.f};
            c = __builtin_amdgcn_mfma_f32_16x16x32_f16(aQ0[g], b0, c, 0, 0, 0);
            c = __builtin_amdgcn_mfma_f32_16x16x32_f16(aQ1[g], b1, c, 0, 0, 0);
            #pragma unroll
            for (int r = 0; r < 4; ++r)
                sKV[wave*2304 + (g*16 + quad*4 + r)*72 + t*16 + l16] = (_Float16)c[r];
        }
    // ---- gather RW bias for the swapped consumer layout
    float rwSw[2][2][4];
    #pragma unroll
    for (int g = 0; g < 2; ++g)
        #pragma unroll
        for (int j = 0; j < 2; ++j)
            #pragma unroll
            for (int r = 0; r < 4; ++r) {
                int q32 = g*16 + l16;
                int w   = q32 - j*16 - quad*4 - r + 31;   // 0..62
                rwSw[g][j][r] = (float)sKV[wave*2304 + q32*72 + w];
            }
    __syncthreads();   // G consumed; buf0 region free
    writeKV(0);        // k-tile 0 -> buf0
    loadKV(1);
    __syncthreads();   // buf0 ready

    f32x4 o[2][4];
    #pragma unroll
    for (int g = 0; g < 2; ++g)
        #pragma unroll
        for (int n = 0; n < 4; ++n) o[g][n] = (f32x4){0.f,0.f,0.f,0.f};
    f32x4 lacc[2] = { (f32x4){0.f,0.f,0.f,0.f}, (f32x4){0.f,0.f,0.f,0.f} };
    const hv8 vone = { (_Float16)1.f, (_Float16)1.f, (_Float16)1.f, (_Float16)1.f,
                       (_Float16)1.f, (_Float16)1.f, (_Float16)1.f, (_Float16)1.f };

    for (int kt = 0; kt < 16; ++kt) {
        const int buf = kt & 1;
        if (kt < 15) writeKV(buf ^ 1);
        if (kt < 14) loadKV(kt + 2);

        // ---- rh bias: lane-constant per g (2 x b32)
        float rhq[2][2];
        #pragma unroll
        for (int g = 0; g < 2; ++g) {
            unsigned pr = *(const unsigned*)&sH[wave*32 + g*16 + l16][kt*2];
            rhq[g][0] = (float)(*(const _Float16*)&pr);
            rhq[g][1] = (float)(*((const _Float16*)&pr + 1));
        }

        // ---- swapped QK^T -> S^T; exp2; pack P pairs into u32 words
        //      wpk[g][bb][rr] = (P[q][k=bb*16+quad*4+2rr], ...+2rr+1)
        unsigned wpk[2][4][2];
        #pragma unroll
        for (int bb = 0; bb < 4; ++bb) {
            hv8 bK0 = *(const hv8*)&sKV[KOFFB(buf) + (bb*16 + l16)*72 + quad*8];
            hv8 bK1 = *(const hv8*)&sKV[KOFFB(buf) + (bb*16 + l16)*72 + 32 + quad*8];
            #pragma unroll
            for (int g = 0; g < 2; ++g) {
                f32x4 c;
                #pragma unroll
                for (int r = 0; r < 4; ++r)
                    c[r] = rhq[g][bb>>1] + rwSw[g][bb&1][r];
                c = __builtin_amdgcn_mfma_f32_16x16x32_f16(bK0, aQ0[g], c, 0, 0, 0);
                c = __builtin_amdgcn_mfma_f32_16x16x32_f16(bK1, aQ1[g], c, 0, 0, 0);
                #pragma unroll
                for (int rr = 0; rr < 2; ++rr) {
                    union { _Float16 hh[2]; unsigned u; } pu;
                    pu.hh[0] = (_Float16)fast_exp2(c[2*rr]);
                    pu.hh[1] = (_Float16)fast_exp2(c[2*rr+1]);
                    wpk[g][bb][rr] = pu.u;
                }
            }
        }

        // ---- permlane repack: 4-contiguous-k runs -> K=32 A-fragments.
        //      swap32: e=(e0,e1,o0,o1) o=(e2,e3,o2,o3); swap16: e=(e0,e2,o0,o2)
        //      -> e holds j={2rr,2rr+1} (word rr), o holds j={4+2rr,..} (word 2+rr)
        hv8 aP[2][2];
        #pragma unroll
        for (int g = 0; g < 2; ++g)
            #pragma unroll
            for (int kk = 0; kk < 2; ++kk) {
                union { unsigned u4[4]; hv8 v; } cv;
                #pragma unroll
                for (int rr = 0; rr < 2; ++rr) {
                    unsigned e = wpk[g][2*kk][rr];
                    unsigned oo = wpk[g][2*kk+1][rr];
                    asm("v_permlane32_swap_b32 %0, %1" : "+v"(e), "+v"(oo));
                    asm("v_permlane16_swap_b32 %0, %1" : "+v"(e), "+v"(oo));
                    cv.u4[rr]     = e;
                    cv.u4[2 + rr] = oo;
                }
                aP[g][kk] = cv.v;
            }

        __builtin_amdgcn_s_setprio(1);
        // ---- row-sum via K=32 MFMA with ones-B (4/kt)
        #pragma unroll
        for (int g = 0; g < 2; ++g) {
            lacc[g] = __builtin_amdgcn_mfma_f32_16x16x32_f16(aP[g][0], vone, lacc[g], 0, 0, 0);
            lacc[g] = __builtin_amdgcn_mfma_f32_16x16x32_f16(aP[g][1], vone, lacc[g], 0, 0, 0);
        }
        // ---- O += P @ V  (K=32, bV frags shared across both groups)
        #pragma unroll
        for (int nn = 0; nn < 4; ++nn) {
            hv8 bV0 = *(const hv8*)&sKV[VOFFB(buf) + (nn*16 + l16)*72 + quad*8];
            hv8 bV1 = *(const hv8*)&sKV[VOFFB(buf) + (nn*16 + l16)*72 + 32 + quad*8];
            #pragma unroll
            for (int g = 0; g < 2; ++g) {
                o[g][nn] = __builtin_amdgcn_mfma_f32_16x16x32_f16(aP[g][0], bV0, o[g][nn], 0, 0, 0);
                o[g][nn] = __builtin_amdgcn_mfma_f32_16x16x32_f16(aP[g][1], bV1, o[g][nn], 0, 0, 0);
            }
        }
        __builtin_amdgcn_s_setprio(0);

        __syncthreads();               // tile kt consumed; tile kt+1 visible
    }

    // ---- finalize: /l, fp16 out into [b, t, C]
    #pragma unroll
    for (int g = 0; g < 2; ++g) {
        float inv[4];
        #pragma unroll
        for (int r = 0; r < 4; ++r) inv[r] = 1.f / lacc[g][r];
        #pragma unroll
        for (int n = 0; n < 4; ++n)
            #pragma unroll
            for (int r = 0; r < 4; ++r) {
                int t = qt*128 + wave*32 + g*16 + quad*4 + r;
                size_t addr = ((size_t)b * TT + t) * CC + h*HD + n*16 + l16;
                O[addr] = (_Float16)(o[g][n][r] * inv[r]);
            }
    }
}

// ---------------------------------------------------------------------------
extern "C" void kernel_launch(void* const* d_in, const int* in_sizes, int n_in,
                              void* d_out, int out_size, void* d_ws, size_t ws_size,
                              hipStream_t stream) {
    const float* x   = (const float*)d_in[0];
    const float* ctx = (const float*)d_in[1];
    const float* Wq  = (const float*)d_in[2];
    const float* Wk  = (const float*)d_in[3];
    const float* Wv  = (const float*)d_in[4];
    const float* Wo  = (const float*)d_in[5];
    const float* bo  = (const float*)d_in[6];
    const float* rh  = (const float*)d_in[7];
    const float* rw  = (const float*)d_in[8];
    float* out = (float*)d_out;

    const size_t MN = (size_t)BB * TT * CC;   // 6291456
    const size_t WN = (size_t)CC * CC;        // 589824
    _Float16* p = (_Float16*)d_ws;
    _Float16* xh  = p; p += MN;
    _Float16* ch  = p; p += MN;
    _Float16* WqT = p; p += WN;
    _Float16* WkT = p; p += WN;
    _Float16* WvT = p; p += WN;
    _Float16* WoT = p; p += WN;
    _Float16* Qh  = p; p += MN;
    _Float16* Kh  = p; p += MN;
    _Float16* VtB = p; p += MN;
    _Float16* Oh  = p; p += MN;

    dim3 blk(256);

    prep_fused<<<dim3(6720), blk, 0, stream>>>(
        x, ctx, xh, ch, (int)MN, Wq, Wk, Wv, Wo, WqT, WkT, WvT, WoT);

    gemm_qkv3<<<dim3(1152), blk, 0, stream>>>(
        xh, ch, WqT, WkT, WvT, Qh, Kh, VtB);

    attn_mfma<<<dim3(BB*NH*(TT/128)), blk, 0, stream>>>(
        Qh, Kh, VtB, rh, rw, Oh);

    gemm_out_f16<<<dim3(768), blk, 0, stream>>>(
        Oh, WoT, bo, out);
}